// Round 1
// baseline (33.830 us; speedup 1.0000x reference)
//
#include <hip/hip_runtime.h>

#define RR 256
#define LAMBDA_TV 1e-5f
#define TV_EPS 1e-9f

// One thread per sparse cell.
// cell = x*R^2 + y*R + z  =>  links[x,y,z] == links_flat[cell]
// neighbors: +x -> cell + R*R, +y -> cell + R, +z -> cell + 1
__global__ void tv_grad_kernel(const float* __restrict__ density,
                               const int* __restrict__ links,
                               const int* __restrict__ cells,
                               float* __restrict__ grad,
                               int num_cells) {
    int i = blockIdx.x * blockDim.x + threadIdx.x;
    if (i >= num_cells) return;

    int cell = cells[i];
    int z = cell & (RR - 1);
    int y = (cell >> 8) & (RR - 1);
    int x = cell >> 16;

    bool in100 = (x + 1 < RR);
    bool in010 = (y + 1 < RR);
    bool in001 = (z + 1 < RR);

    int l000 = links[cell];
    int l100 = in100 ? links[cell + RR * RR] : -1;
    int l010 = in010 ? links[cell + RR] : -1;
    int l001 = in001 ? links[cell + 1] : -1;

    float v000 = (l000 >= 0) ? density[l000] : 0.0f;
    float v100 = in100 ? ((l100 >= 0) ? density[l100] : 0.0f) : v000;
    float v010 = in010 ? ((l010 >= 0) ? density[l010] : 0.0f) : v000;
    float v001 = in001 ? ((l001 >= 0) ? density[l001] : 0.0f) : v000;

    const float s = RR * 0.5f;
    float dx = (v100 - v000) * s;
    float dy = (v010 - v000) * s;
    float dz = (v001 - v000) * s;

    float idelta = LAMBDA_TV * rsqrtf(TV_EPS + dx * dx + dy * dy + dz * dz);

    if (l000 >= 0) atomicAdd(&grad[l000], -(dx + dy + dz) * idelta);
    if (l100 >= 0) atomicAdd(&grad[l100], dx * idelta);
    if (l010 >= 0) atomicAdd(&grad[l010], dy * idelta);
    if (l001 >= 0) atomicAdd(&grad[l001], dz * idelta);
}

extern "C" void kernel_launch(void* const* d_in, const int* in_sizes, int n_in,
                              void* d_out, int out_size, void* d_ws, size_t ws_size,
                              hipStream_t stream) {
    const float* density = (const float*)d_in[0];   // (N, 1) f32
    const int* links     = (const int*)d_in[1];     // (R, R, R) i32
    const int* cells     = (const int*)d_in[2];     // (sparse_num,) i32
    float* out           = (float*)d_out;           // (N, 1) f32

    int num_cells = in_sizes[2];

    // Output must be zeroed every call (atomic scatter accumulates otherwise;
    // harness does not re-poison between replays).
    hipMemsetAsync(out, 0, (size_t)out_size * sizeof(float), stream);

    const int threads = 256;
    int blocks = (num_cells + threads - 1) / threads;
    tv_grad_kernel<<<blocks, threads, 0, stream>>>(density, links, cells, out, num_cells);
}

// Round 2
// 33.520 us; speedup vs baseline: 1.0092x; 1.0092x over previous
//
#include <hip/hip_runtime.h>

#define RR 256
#define LAMBDA_TV 1e-5f
#define TV_EPS 1e-9f

// Grid-stride float4 zeroing — the runtime's fillBufferAligned picked a bad
// config (829 GB/s, 40 µs for 33.5 MB). 2048 blocks x 256 thr hits ~6 TB/s.
__global__ void zero_kernel(float4* __restrict__ out, int n4) {
    int i = blockIdx.x * blockDim.x + threadIdx.x;
    int stride = gridDim.x * blockDim.x;
    for (; i < n4; i += stride) {
        out[i] = make_float4(0.0f, 0.0f, 0.0f, 0.0f);
    }
}

// One thread per sparse cell.
// cell = x*R^2 + y*R + z  =>  links[x,y,z] == links_flat[cell]
// neighbors: +x -> cell + R*R, +y -> cell + R, +z -> cell + 1
__global__ void tv_grad_kernel(const float* __restrict__ density,
                               const int* __restrict__ links,
                               const int* __restrict__ cells,
                               float* __restrict__ grad,
                               int num_cells) {
    int i = blockIdx.x * blockDim.x + threadIdx.x;
    if (i >= num_cells) return;

    int cell = cells[i];
    int z = cell & (RR - 1);
    int y = (cell >> 8) & (RR - 1);
    int x = cell >> 16;

    bool in100 = (x + 1 < RR);
    bool in010 = (y + 1 < RR);
    bool in001 = (z + 1 < RR);

    int l000 = links[cell];
    int l100 = in100 ? links[cell + RR * RR] : -1;
    int l010 = in010 ? links[cell + RR] : -1;
    int l001 = in001 ? links[cell + 1] : -1;

    float v000 = (l000 >= 0) ? density[l000] : 0.0f;
    float v100 = in100 ? ((l100 >= 0) ? density[l100] : 0.0f) : v000;
    float v010 = in010 ? ((l010 >= 0) ? density[l010] : 0.0f) : v000;
    float v001 = in001 ? ((l001 >= 0) ? density[l001] : 0.0f) : v000;

    const float s = RR * 0.5f;
    float dx = (v100 - v000) * s;
    float dy = (v010 - v000) * s;
    float dz = (v001 - v000) * s;

    float idelta = LAMBDA_TV * rsqrtf(TV_EPS + dx * dx + dy * dy + dz * dz);

    if (l000 >= 0) atomicAdd(&grad[l000], -(dx + dy + dz) * idelta);
    if (l100 >= 0) atomicAdd(&grad[l100], dx * idelta);
    if (l010 >= 0) atomicAdd(&grad[l010], dy * idelta);
    if (l001 >= 0) atomicAdd(&grad[l001], dz * idelta);
}

extern "C" void kernel_launch(void* const* d_in, const int* in_sizes, int n_in,
                              void* d_out, int out_size, void* d_ws, size_t ws_size,
                              hipStream_t stream) {
    const float* density = (const float*)d_in[0];   // (N, 1) f32
    const int* links     = (const int*)d_in[1];     // (R, R, R) i32
    const int* cells     = (const int*)d_in[2];     // (sparse_num,) i32
    float* out           = (float*)d_out;           // (N, 1) f32

    int num_cells = in_sizes[2];

    // Output must be zeroed every call (atomic scatter accumulates otherwise;
    // harness poisons d_out before timing and does not re-poison between
    // replays). out_size = 8388608, divisible by 4.
    int n4 = out_size / 4;
    zero_kernel<<<2048, 256, 0, stream>>>((float4*)out, n4);

    const int threads = 256;
    int blocks = (num_cells + threads - 1) / threads;
    tv_grad_kernel<<<blocks, threads, 0, stream>>>(density, links, cells, out, num_cells);
}